// Round 2
// baseline (7457.764 us; speedup 1.0000x reference)
//
#include <hip/hip_runtime.h>
#include <hip/hip_fp16.h>

#define NT    365
#define NGRID 1000
#define NXI   20
#define HID   256
#define GATES 1024
#define KTOT  512          // 256 (x0) + 256 (h)
#define BN    4            // grid points per block
#define NBLK  (NGRID / BN) // 250
#define PF    8            // weight prefetch depth (k2 slices in flight)

typedef float v4f __attribute__((ext_vector_type(4)));

// Packed [W_ih | W_hh] as fp16 pairs, layout g_wp[k2*1024 + g].
// Module-scope global: d_ws turned out to be < 1MB (OOB writes there corrupted
// the harness's pristine input copies). .bss allocation is safe + persistent;
// we fully rewrite it on every launch so graph replays do identical work.
__device__ unsigned int g_wp[(KTOT / 2) * GATES];

__device__ __forceinline__ float fsig(float x) {
  return __fdividef(1.f, 1.f + __expf(-x));
}
__device__ __forceinline__ float ftanh(float x) {
  return 1.f - __fdividef(2.f, __expf(2.f * x) + 1.f);
}
__device__ __forceinline__ float cell_update(float gi, float gf, float gg, float go, float& c) {
  const float i_ = fsig(gi);
  const float f_ = fsig(gf);
  const float g_ = ftanh(gg);
  const float o_ = fsig(go);
  c = f_ * c + i_ * g_;
  return o_ * ftanh(c);
}

__global__ __launch_bounds__(256) void prep_weights_kernel(
    const float* __restrict__ W_ih, const float* __restrict__ W_hh) {
  const int tid = blockIdx.x * 256 + threadIdx.x; // = k2*1024 + g, 0..262143
  const int k2 = tid >> 10;
  const int g  = tid & 1023;
  const int k0 = k2 * 2;
  const float* src = (k0 < HID) ? (W_ih + g * HID + k0) : (W_hh + g * HID + (k0 - HID));
  __half2 h2;
  h2.x = __float2half(src[0]);
  h2.y = __float2half(src[1]);
  g_wp[tid] = *(const unsigned int*)&h2;
}

__global__ __launch_bounds__(256) void lstm_kernel(
    const float* __restrict__ x,      // [NT][NGRID][NXI]
    const float* __restrict__ W_in,   // [HID][NXI]
    const float* __restrict__ b_in,   // [HID]
    const float* __restrict__ b_ih,   // [GATES]
    const float* __restrict__ b_hh,   // [GATES]
    const float* __restrict__ W_out,  // [1][HID]
    const float* __restrict__ b_out,  // [1]
    float* __restrict__ y)            // [NT][NGRID]
{
  __shared__ float s_Win[HID][NXI + 1]; // +1 pad: stride 21 coprime with 32 banks
  __shared__ float s_a[BN][KTOT];       // [p][k]: k<256 -> x0(t), k>=256 -> h(t-1)
  __shared__ float s_c[BN][HID];
  __shared__ float s_g[BN][GATES];      // pre-activation gates
  __shared__ float s_xt[BN * NXI];

  const int tid  = threadIdx.x;
  const int lane = tid & 63;
  const int wave = tid >> 6;
  const int n0   = blockIdx.x * BN;

  // one-time setup
  for (int i = tid; i < HID * NXI; i += 256) s_Win[i / NXI][i % NXI] = W_in[i];
  const float my_bin = b_in[tid];
  float mb0, mb1, mb2, mb3; // combined bias for my 4 gates g = 4*tid + q
  {
    const float4 bi = *(const float4*)(b_ih + tid * 4);
    const float4 bh = *(const float4*)(b_hh + tid * 4);
    mb0 = bi.x + bh.x; mb1 = bi.y + bh.y; mb2 = bi.z + bh.z; mb3 = bi.w + bh.w;
  }
  const float4 wo = *(const float4*)(W_out + lane * 4);
  const float bo = b_out[0];

  for (int i = tid; i < BN * HID; i += 256) {
    const int p = i >> 8, d = i & 255;
    s_c[p][d] = 0.f;
    s_a[p][HID + d] = 0.f; // h = 0
  }
  __syncthreads();

  const unsigned int* wrow = g_wp + (tid << 2);

  for (int t = 0; t < NT; ++t) {
    // stage x_t for our 4 grid points (80 consecutive floats)
    if (tid < BN * NXI)
      s_xt[tid] = x[((size_t)t * NGRID + n0) * NXI + tid];
    __syncthreads(); // (A)

    // x0 = relu(x @ W_in.T + b_in): thread j computes hidden unit j for all 4 points
    #pragma unroll
    for (int p = 0; p < BN; ++p) {
      float v = my_bin;
      #pragma unroll
      for (int k = 0; k < NXI; ++k) v += s_xt[p * NXI + k] * s_Win[tid][k];
      s_a[p][tid] = fmaxf(v, 0.f);
    }
    __syncthreads(); // (B)

    // gates = [x0, h] @ [W_ih | W_hh].T + (b_ih + b_hh)
    // thread j owns gates 4j..4j+3 for all 4 points; weights streamed fp16 from
    // L2 with an explicit depth-PF prefetch pipeline (PF dwordx4 in flight).
    v4f acc0 = {mb0, mb0, mb0, mb0};
    v4f acc1 = {mb1, mb1, mb1, mb1};
    v4f acc2 = {mb2, mb2, mb2, mb2};
    v4f acc3 = {mb3, mb3, mb3, mb3};

    uint4 wbuf[PF];
    #pragma unroll
    for (int j = 0; j < PF; ++j) wbuf[j] = *(const uint4*)(wrow + (j << 10));

    for (int kb = 0; kb < KTOT / 2; kb += PF) {
      uint4 nbuf[PF];
      const int nb = (kb + PF < KTOT / 2) ? (kb + PF) : 0; // wrap: dead loads on last iter
      #pragma unroll
      for (int j = 0; j < PF; ++j) nbuf[j] = *(const uint4*)(wrow + ((nb + j) << 10));

      #pragma unroll
      for (int j = 0; j < PF; ++j) {
        const int k2 = kb + j;
        const uint4 w = wbuf[j];
        const float2 a0 = *(const float2*)&s_a[0][k2 * 2]; // LDS broadcasts
        const float2 a1 = *(const float2*)&s_a[1][k2 * 2];
        const float2 a2 = *(const float2*)&s_a[2][k2 * 2];
        const float2 a3 = *(const float2*)&s_a[3][k2 * 2];
        const v4f ax = {a0.x, a1.x, a2.x, a3.x};
        const v4f ay = {a0.y, a1.y, a2.y, a3.y};
        const float2 w0 = __half22float2(*(const __half2*)&w.x);
        const float2 w1 = __half22float2(*(const __half2*)&w.y);
        const float2 w2 = __half22float2(*(const __half2*)&w.z);
        const float2 w3 = __half22float2(*(const __half2*)&w.w);
        acc0 += w0.x * ax; acc0 += w0.y * ay;
        acc1 += w1.x * ax; acc1 += w1.y * ay;
        acc2 += w2.x * ax; acc2 += w2.y * ay;
        acc3 += w3.x * ax; acc3 += w3.y * ay;
      }
      #pragma unroll
      for (int j = 0; j < PF; ++j) wbuf[j] = nbuf[j];
    }

    #pragma unroll
    for (int p = 0; p < BN; ++p) {
      const float4 gv = make_float4(acc0[p], acc1[p], acc2[p], acc3[p]);
      *(float4*)&s_g[p][tid * 4] = gv;
    }
    __syncthreads(); // (C)

    // h/c update + output projection: wave p handles point p, lane covers dims 4l..4l+3
    {
      const int p = wave;
      const int d = lane * 4;
      const float4 gi = *(const float4*)&s_g[p][d];
      const float4 gf = *(const float4*)&s_g[p][HID + d];
      const float4 gg = *(const float4*)&s_g[p][2 * HID + d];
      const float4 go = *(const float4*)&s_g[p][3 * HID + d];
      float4 cc = *(const float4*)&s_c[p][d];
      float h0, h1, h2, h3;
      h0 = cell_update(gi.x, gf.x, gg.x, go.x, cc.x);
      h1 = cell_update(gi.y, gf.y, gg.y, go.y, cc.y);
      h2 = cell_update(gi.z, gf.z, gg.z, go.z, cc.z);
      h3 = cell_update(gi.w, gf.w, gg.w, go.w, cc.w);
      *(float4*)&s_c[p][d] = cc;
      *(float4*)&s_a[p][HID + d] = make_float4(h0, h1, h2, h3);
      float part = h0 * wo.x + h1 * wo.y + h2 * wo.z + h3 * wo.w;
      part += __shfl_xor(part, 1);
      part += __shfl_xor(part, 2);
      part += __shfl_xor(part, 4);
      part += __shfl_xor(part, 8);
      part += __shfl_xor(part, 16);
      part += __shfl_xor(part, 32);
      if (lane == 0) y[(size_t)t * NGRID + n0 + p] = part + bo;
    }
    // no barrier needed here: next iter's (A)/(B) order s_g/s_a reuse
  }
}

extern "C" void kernel_launch(void* const* d_in, const int* in_sizes, int n_in,
                              void* d_out, int out_size, void* d_ws, size_t ws_size,
                              hipStream_t stream) {
  (void)in_sizes; (void)n_in; (void)out_size; (void)d_ws; (void)ws_size;
  const float* x     = (const float*)d_in[0];
  // d_in[1] = wt_ih (zeros in eval mode, unused)
  const float* W_in  = (const float*)d_in[2];
  const float* b_in  = (const float*)d_in[3];
  const float* W_ih  = (const float*)d_in[4];
  const float* W_hh  = (const float*)d_in[5];
  const float* b_ih  = (const float*)d_in[6];
  const float* b_hh  = (const float*)d_in[7];
  const float* W_out = (const float*)d_in[8];
  const float* b_out = (const float*)d_in[9];
  float* y           = (float*)d_out;

  hipLaunchKernelGGL(prep_weights_kernel, dim3(1024), dim3(256), 0, stream,
                     W_ih, W_hh);
  hipLaunchKernelGGL(lstm_kernel, dim3(NBLK), dim3(256), 0, stream,
                     x, W_in, b_in, b_ih, b_hh, W_out, b_out, y);
}

// Round 3
// 6695.054 us; speedup vs baseline: 1.1139x; 1.1139x over previous
//
#include <hip/hip_runtime.h>
#include <hip/hip_fp16.h>

#define NT    365
#define NGRID 1000
#define NXI   20
#define HID   256
#define GATES 1024
#define MROWS 365000          // NT*NGRID
#define MBLK  5704            // ceil(MROWS/64)
#define MPAD  (MBLK * 64)     // 365056
#define BN    8               // grid points per recurrent block
#define NBLK  (NGRID / BN)    // 125

typedef _Float16 half8 __attribute__((ext_vector_type(8)));
typedef float floatx4 __attribute__((ext_vector_type(4)));

// Module-scope device globals (d_ws is too small; 1MB global worked in R1).
// Rewritten fully every launch -> graph replays do identical work.
__device__ _Float16 g_x0f[(size_t)MPAD * HID];    // x0 in A-fragment layout, 187MB
__device__ _Float16 g_gx[(size_t)MPAD * GATES];   // input-gate contrib + biases, 747MB
__device__ _Float16 g_wif[64 * 8 * 512];          // W_ih in B-fragment layout, 512KB
__device__ _Float16 g_whf[64 * 8 * 512];          // W_hh in B-fragment layout, 512KB

__device__ __forceinline__ float fsig(float x) {
  return __fdividef(1.f, 1.f + __expf(-x));
}
__device__ __forceinline__ float ftanh(float x) {
  return 1.f - __fdividef(2.f, __expf(2.f * x) + 1.f);
}

// ---- pack W_ih / W_hh into MFMA B-fragment layout -------------------------
// B-frag for 16x16x32: lane holds B[n = tile*16 + (lane&15)][k = ks*32 + (lane>>4)*8 + j]
// storage: wf[((tile*8 + ks)*64 + lane)*8 + j]
__global__ __launch_bounds__(256) void pack_wf_kernel(
    const float* __restrict__ W_ih, const float* __restrict__ W_hh) {
  const int gid  = blockIdx.x * 256 + threadIdx.x;  // 0..65535
  const int mat  = gid >> 15;
  const int rem  = gid & 32767;
  const int tile = rem >> 9;
  const int ks   = (rem >> 6) & 7;
  const int lane = rem & 63;
  const int n    = tile * 16 + (lane & 15);
  const int k0   = ks * 32 + (lane >> 4) * 8;
  const float* src = (mat ? W_hh : W_ih) + n * HID + k0;
  _Float16* dst = (mat ? g_whf : g_wif) + ((tile * 8 + ks) * 64 + lane) * 8;
  const float4 a = *(const float4*)(src);
  const float4 b = *(const float4*)(src + 4);
  half8 h;
  h[0] = (_Float16)a.x; h[1] = (_Float16)a.y; h[2] = (_Float16)a.z; h[3] = (_Float16)a.w;
  h[4] = (_Float16)b.x; h[5] = (_Float16)b.y; h[6] = (_Float16)b.z; h[7] = (_Float16)b.w;
  *(half8*)dst = h;
}

// ---- x0 = relu(x @ W_in.T + b_in), stored in A-fragment layout ------------
// A-frag: lane holds A[m = mt*16 + (lane&15)][k = kt*32 + (lane>>4)*8 + j]
// storage: g_x0f[((mt*8 + kt)*64 + lane)*8 + j]
__global__ __launch_bounds__(256) void x0f_kernel(
    const float* __restrict__ x, const float* __restrict__ W_in,
    const float* __restrict__ b_in) {
  __shared__ float s_x[64 * NXI];            // 64 rows of x
  __shared__ _Float16 s_x0[64 * 264];        // 64 x 256 (+8 pad)

  const int tid = threadIdx.x;
  const int m0  = blockIdx.x * 64;

  // stage 64 rows of x (clamped for the padded tail)
  #pragma unroll
  for (int i = 0; i < 5; ++i) {
    const int idx = i * 256 + tid;           // 0..1279
    size_t g = (size_t)m0 * NXI + idx;
    const size_t gmax = (size_t)MROWS * NXI - 1;
    if (g > gmax) g = gmax;
    s_x[idx] = x[g];
  }
  float wv[NXI];
  #pragma unroll
  for (int k = 0; k < NXI; ++k) wv[k] = W_in[tid * NXI + k];
  const float bv = b_in[tid];
  __syncthreads();

  for (int r = 0; r < 64; ++r) {
    float acc = bv;
    #pragma unroll
    for (int q = 0; q < 5; ++q) {
      const float4 xa = *(const float4*)&s_x[r * NXI + q * 4];
      acc += xa.x * wv[q * 4 + 0] + xa.y * wv[q * 4 + 1] +
             xa.z * wv[q * 4 + 2] + xa.w * wv[q * 4 + 3];
    }
    s_x0[r * 264 + tid] = (_Float16)fmaxf(acc, 0.f);
  }
  __syncthreads();

  // repack LDS -> fragment layout, coalesced dwordx4 stores
  #pragma unroll
  for (int it = 0; it < 8; ++it) {
    const int work = it * 256 + tid;         // 0..2047
    const int f    = work >> 6;              // fragment 0..31 = mtl*8 + kt
    const int l    = work & 63;
    const int mtl  = f >> 3;
    const int kt   = f & 7;
    const int r    = mtl * 16 + (l & 15);
    const int c    = kt * 32 + (l >> 4) * 8;
    const half8 v  = *(const half8*)&s_x0[r * 264 + c];
    const int mt   = (m0 >> 4) + mtl;
    *(half8*)(g_x0f + ((size_t)(mt * 8 + kt) * 64 + l) * 8) = v;
  }
}

// ---- gx = x0 @ W_ih.T + (b_ih + b_hh), fp16, for all rows -----------------
// grid: MBLK*4 blocks; block covers 64 rows x 256 gates; 4 waves, each 64x64.
__global__ __launch_bounds__(256) void gx_kernel(
    const float* __restrict__ b_ih, const float* __restrict__ b_hh) {
  __shared__ _Float16 s_out[64 * 264];

  const int tid  = threadIdx.x;
  const int lane = tid & 63;
  const int w    = tid >> 6;
  const int mb   = blockIdx.x >> 2;
  const int ng   = blockIdx.x & 3;

  floatx4 acc[4][4];
  #pragma unroll
  for (int mi = 0; mi < 4; ++mi)
    #pragma unroll
    for (int ni = 0; ni < 4; ++ni) acc[mi][ni] = (floatx4){0.f, 0.f, 0.f, 0.f};

  #pragma unroll
  for (int ks = 0; ks < 8; ++ks) {
    half8 a[4], b[4];
    #pragma unroll
    for (int mi = 0; mi < 4; ++mi) {
      const int mt = mb * 4 + mi;
      a[mi] = *(const half8*)(g_x0f + ((size_t)(mt * 8 + ks) * 64 + lane) * 8);
    }
    #pragma unroll
    for (int ni = 0; ni < 4; ++ni) {
      const int nt = ng * 16 + w * 4 + ni;
      b[ni] = *(const half8*)(g_wif + ((size_t)(nt * 8 + ks) * 64 + lane) * 8);
    }
    #pragma unroll
    for (int mi = 0; mi < 4; ++mi)
      #pragma unroll
      for (int ni = 0; ni < 4; ++ni)
        acc[mi][ni] = __builtin_amdgcn_mfma_f32_16x16x32_f16(a[mi], b[ni], acc[mi][ni], 0, 0, 0);
  }

  // epilogue: + (b_ih + b_hh), write to LDS window, then coalesced f16 stores
  #pragma unroll
  for (int ni = 0; ni < 4; ++ni) {
    const int g = ng * 256 + (w * 4 + ni) * 16 + (lane & 15);
    const float bias = b_ih[g] + b_hh[g];
    const int colw = (w * 4 + ni) * 16 + (lane & 15);
    #pragma unroll
    for (int mi = 0; mi < 4; ++mi) {
      #pragma unroll
      for (int r = 0; r < 4; ++r) {
        const int row = mi * 16 + (lane >> 4) * 4 + r;
        s_out[row * 264 + colw] = (_Float16)(acc[mi][ni][r] + bias);
      }
    }
  }
  __syncthreads();

  #pragma unroll
  for (int i = 0; i < 8; ++i) {
    const int cid = i * 256 + tid;           // 0..2047 chunks of 16B
    const int row = cid >> 5;
    const int c8  = (cid & 31) * 8;
    const half8 v = *(const half8*)&s_out[row * 264 + c8];
    *(half8*)(g_gx + (size_t)(mb * 64 + row) * GATES + ng * 256 + c8) = v;
  }
}

// ---- recurrent kernel: 125 blocks x 8 points, MFMA h @ W_hh.T -------------
__global__ __launch_bounds__(256) void rec_kernel(
    const float* __restrict__ W_out, const float* __restrict__ b_out,
    float* __restrict__ y) {
  __shared__ _Float16 s_hf[16 * 264];   // h in A-fragment-friendly rows (8.4KB)
  __shared__ float s_g[16 * 1024];      // mfma gate accum (64KB)

  const int tid  = threadIdx.x;
  const int lane = tid & 63;
  const int w    = tid >> 6;
  const int n0   = blockIdx.x * BN;
  const int p    = tid >> 5;            // 0..7 point
  const int d0   = (tid & 31) * 8;      // 8 hidden dims per thread

  // init: h rows (incl. zero-pad rows 8..15) = 0
  for (int i = tid; i < 16 * 264 / 2; i += 256) ((unsigned int*)s_hf)[i] = 0u;
  float c[8];
  #pragma unroll
  for (int j = 0; j < 8; ++j) c[j] = 0.f;
  float wo[8];
  #pragma unroll
  for (int j = 0; j < 8; ++j) wo[j] = W_out[d0 + j];
  const float bo = b_out[0];
  __syncthreads();

  const _Float16* wbase = g_whf + (size_t)w * 16 * 8 * 512;
  const int a_off = (lane & 15) * 264 + (lane >> 4) * 8;

  for (int t = 0; t < NT; ++t) {
    // A-fragments for this step's h (all 8 k-steps)
    half8 af[8];
    #pragma unroll
    for (int ks = 0; ks < 8; ++ks)
      af[ks] = *(const half8*)&s_hf[a_off + ks * 32];

    // 16 gate-tiles per wave, depth-3 weight-fragment pipeline from L2
    half8 bb[3][8];
    #pragma unroll
    for (int i = 0; i < 3; ++i)
      #pragma unroll
      for (int ks = 0; ks < 8; ++ks)
        bb[i][ks] = *(const half8*)(wbase + ((size_t)(i * 8 + ks) * 64 + lane) * 8);

    #pragma unroll
    for (int i = 0; i < 16; ++i) {
      floatx4 acc = (floatx4){0.f, 0.f, 0.f, 0.f};
      #pragma unroll
      for (int ks = 0; ks < 8; ++ks)
        acc = __builtin_amdgcn_mfma_f32_16x16x32_f16(af[ks], bb[i % 3][ks], acc, 0, 0, 0);
      if (i < 13) {
        #pragma unroll
        for (int ks = 0; ks < 8; ++ks)
          bb[i % 3][ks] = *(const half8*)(wbase + ((size_t)((i + 3) * 8 + ks) * 64 + lane) * 8);
      }
      const int nt = w * 16 + i;
      const int col = nt * 16 + (lane & 15);
      #pragma unroll
      for (int r = 0; r < 4; ++r)
        s_g[((lane >> 4) * 4 + r) * 1024 + col] = acc[r];
    }
    __syncthreads();

    // cell update: thread owns (point p, dims d0..d0+7)
    {
      const int row = t * NGRID + n0 + p;
      const _Float16* gxp = g_gx + (size_t)row * GATES + d0;
      const half8 xi = *(const half8*)(gxp);
      const half8 xf = *(const half8*)(gxp + 256);
      const half8 xg = *(const half8*)(gxp + 512);
      const half8 xo = *(const half8*)(gxp + 768);
      const float* sgp = &s_g[p * 1024 + d0];
      float yp = 0.f;
      half8 hh;
      #pragma unroll
      for (int j = 0; j < 8; ++j) {
        const float gi = sgp[j]       + (float)xi[j];
        const float gf = sgp[256 + j] + (float)xf[j];
        const float gg = sgp[512 + j] + (float)xg[j];
        const float go = sgp[768 + j] + (float)xo[j];
        const float i_ = fsig(gi);
        const float f_ = fsig(gf);
        const float g_ = ftanh(gg);
        const float o_ = fsig(go);
        c[j] = f_ * c[j] + i_ * g_;
        const float h = o_ * ftanh(c[j]);
        hh[j] = (_Float16)h;
        yp += wo[j] * h;
      }
      *(half8*)&s_hf[p * 264 + d0] = hh;
      yp += __shfl_xor(yp, 1);
      yp += __shfl_xor(yp, 2);
      yp += __shfl_xor(yp, 4);
      yp += __shfl_xor(yp, 8);
      yp += __shfl_xor(yp, 16);
      if ((tid & 31) == 0) y[t * NGRID + n0 + p] = yp + bo;
    }
    __syncthreads();
  }
}

extern "C" void kernel_launch(void* const* d_in, const int* in_sizes, int n_in,
                              void* d_out, int out_size, void* d_ws, size_t ws_size,
                              hipStream_t stream) {
  (void)in_sizes; (void)n_in; (void)out_size; (void)d_ws; (void)ws_size;
  const float* x     = (const float*)d_in[0];
  // d_in[1] = wt_ih (zeros in eval mode, unused)
  const float* W_in  = (const float*)d_in[2];
  const float* b_in  = (const float*)d_in[3];
  const float* W_ih  = (const float*)d_in[4];
  const float* W_hh  = (const float*)d_in[5];
  const float* b_ih  = (const float*)d_in[6];
  const float* b_hh  = (const float*)d_in[7];
  const float* W_out = (const float*)d_in[8];
  const float* b_out = (const float*)d_in[9];
  float* y           = (float*)d_out;

  hipLaunchKernelGGL(pack_wf_kernel, dim3(256), dim3(256), 0, stream, W_ih, W_hh);
  hipLaunchKernelGGL(x0f_kernel, dim3(MBLK), dim3(256), 0, stream, x, W_in, b_in);
  hipLaunchKernelGGL(gx_kernel, dim3(MBLK * 4), dim3(256), 0, stream, b_ih, b_hh);
  hipLaunchKernelGGL(rec_kernel, dim3(NBLK), dim3(256), 0, stream, W_out, b_out, y);
}

// Round 4
// 6235.288 us; speedup vs baseline: 1.1961x; 1.0737x over previous
//
#include <hip/hip_runtime.h>
#include <hip/hip_fp16.h>

#define NT    365
#define NGRID 1000
#define NXI   20
#define HID   256
#define GATES 1024
#define MROWS 365000          // NT*NGRID
#define MBLK  5704            // ceil(MROWS/64)
#define MPAD  (MBLK * 64)
#define NCL   63              // clusters (16 pts each, last one ragged)
#define CPTS  16              // grid points per cluster

typedef _Float16 half8 __attribute__((ext_vector_type(8)));
typedef float floatx4 __attribute__((ext_vector_type(4)));
typedef unsigned long long u64;

// Module-scope globals (d_ws is too small). Fully rewritten / reset each launch.
__device__ _Float16 g_x0f[(size_t)MPAD * HID];    // x0 in A-fragment layout
__device__ _Float16 g_gx[(size_t)MPAD * GATES];   // gx, block-permuted columns
__device__ _Float16 g_wif[64 * 8 * 512];          // W_ih B-fragments
__device__ _Float16 g_whf[64 * 8 * 512];          // W_hh B-fragments
__device__ u64          g_hx[2][NCL][1024];       // h exchange, dbl-buffered by t parity
__device__ unsigned int g_cnt[NCL];               // per-cluster step counters

__device__ __forceinline__ float fsig(float x) {
  return __fdividef(1.f, 1.f + __expf(-x));
}
__device__ __forceinline__ float ftanh(float x) {
  return 1.f - __fdividef(2.f, __expf(2.f * x) + 1.f);
}

// ---- init: zero y (atomicAdd target) and cluster counters -----------------
__global__ __launch_bounds__(256) void init_kernel(float* __restrict__ y) {
  const int i = blockIdx.x * 256 + threadIdx.x;
  if (i < MROWS) y[i] = 0.f;
  if (i < NCL) g_cnt[i] = 0u;
}

// ---- pack W_ih / W_hh into MFMA B-fragment layout -------------------------
__global__ __launch_bounds__(256) void pack_wf_kernel(
    const float* __restrict__ W_ih, const float* __restrict__ W_hh) {
  const int gid  = blockIdx.x * 256 + threadIdx.x;  // 0..65535
  const int mat  = gid >> 15;
  const int rem  = gid & 32767;
  const int tile = rem >> 9;
  const int ks   = (rem >> 6) & 7;
  const int lane = rem & 63;
  const int n    = tile * 16 + (lane & 15);
  const int k0   = ks * 32 + (lane >> 4) * 8;
  const float* src = (mat ? W_hh : W_ih) + n * HID + k0;
  _Float16* dst = (mat ? g_whf : g_wif) + ((tile * 8 + ks) * 64 + lane) * 8;
  const float4 a = *(const float4*)(src);
  const float4 b = *(const float4*)(src + 4);
  half8 h;
  h[0] = (_Float16)a.x; h[1] = (_Float16)a.y; h[2] = (_Float16)a.z; h[3] = (_Float16)a.w;
  h[4] = (_Float16)b.x; h[5] = (_Float16)b.y; h[6] = (_Float16)b.z; h[7] = (_Float16)b.w;
  *(half8*)dst = h;
}

// ---- x0 = relu(x @ W_in.T + b_in) in A-fragment layout --------------------
__global__ __launch_bounds__(256) void x0f_kernel(
    const float* __restrict__ x, const float* __restrict__ W_in,
    const float* __restrict__ b_in) {
  __shared__ float s_x[64 * NXI];
  __shared__ _Float16 s_x0[64 * 264];

  const int tid = threadIdx.x;
  const int m0  = blockIdx.x * 64;

  #pragma unroll
  for (int i = 0; i < 5; ++i) {
    const int idx = i * 256 + tid;
    size_t g = (size_t)m0 * NXI + idx;
    const size_t gmax = (size_t)MROWS * NXI - 1;
    if (g > gmax) g = gmax;
    s_x[idx] = x[g];
  }
  float wv[NXI];
  #pragma unroll
  for (int k = 0; k < NXI; ++k) wv[k] = W_in[tid * NXI + k];
  const float bv = b_in[tid];
  __syncthreads();

  for (int r = 0; r < 64; ++r) {
    float acc = bv;
    #pragma unroll
    for (int q = 0; q < 5; ++q) {
      const float4 xa = *(const float4*)&s_x[r * NXI + q * 4];
      acc += xa.x * wv[q * 4 + 0] + xa.y * wv[q * 4 + 1] +
             xa.z * wv[q * 4 + 2] + xa.w * wv[q * 4 + 3];
    }
    s_x0[r * 264 + tid] = (_Float16)fmaxf(acc, 0.f);
  }
  __syncthreads();

  #pragma unroll
  for (int it = 0; it < 8; ++it) {
    const int work = it * 256 + tid;
    const int f    = work >> 6;
    const int l    = work & 63;
    const int mtl  = f >> 3;
    const int kt   = f & 7;
    const int r    = mtl * 16 + (l & 15);
    const int c    = kt * 32 + (l >> 4) * 8;
    const half8 v  = *(const half8*)&s_x0[r * 264 + c];
    const int mt   = (m0 >> 4) + mtl;
    *(half8*)(g_x0f + ((size_t)(mt * 8 + kt) * 64 + l) * 8) = v;
  }
}

// ---- gx = x0 @ W_ih.T + (b_ih + b_hh), columns permuted to block-major ----
// column g stored at phi(g) = ((g>>6)&3)*256 + (g>>8)*64 + (g&63)
__global__ __launch_bounds__(256) void gx_kernel(
    const float* __restrict__ b_ih, const float* __restrict__ b_hh) {
  __shared__ _Float16 s_out[64 * 264];

  const int tid  = threadIdx.x;
  const int lane = tid & 63;
  const int w    = tid >> 6;
  const int mb   = blockIdx.x >> 2;
  const int ng   = blockIdx.x & 3;

  floatx4 acc[4][4];
  #pragma unroll
  for (int mi = 0; mi < 4; ++mi)
    #pragma unroll
    for (int ni = 0; ni < 4; ++ni) acc[mi][ni] = (floatx4){0.f, 0.f, 0.f, 0.f};

  #pragma unroll
  for (int ks = 0; ks < 8; ++ks) {
    half8 a[4], b[4];
    #pragma unroll
    for (int mi = 0; mi < 4; ++mi) {
      const int mt = mb * 4 + mi;
      a[mi] = *(const half8*)(g_x0f + ((size_t)(mt * 8 + ks) * 64 + lane) * 8);
    }
    #pragma unroll
    for (int ni = 0; ni < 4; ++ni) {
      const int nt = ng * 16 + w * 4 + ni;
      b[ni] = *(const half8*)(g_wif + ((size_t)(nt * 8 + ks) * 64 + lane) * 8);
    }
    #pragma unroll
    for (int mi = 0; mi < 4; ++mi)
      #pragma unroll
      for (int ni = 0; ni < 4; ++ni)
        acc[mi][ni] = __builtin_amdgcn_mfma_f32_16x16x32_f16(a[mi], b[ni], acc[mi][ni], 0, 0, 0);
  }

  #pragma unroll
  for (int ni = 0; ni < 4; ++ni) {
    const int g = ng * 256 + (w * 4 + ni) * 16 + (lane & 15);
    const float bias = b_ih[g] + b_hh[g];
    const int colw = (w * 4 + ni) * 16 + (lane & 15);
    #pragma unroll
    for (int mi = 0; mi < 4; ++mi) {
      #pragma unroll
      for (int r = 0; r < 4; ++r) {
        const int row = mi * 16 + (lane >> 4) * 4 + r;
        s_out[row * 264 + colw] = (_Float16)(acc[mi][ni][r] + bias);
      }
    }
  }
  __syncthreads();

  #pragma unroll
  for (int i = 0; i < 8; ++i) {
    const int cid = i * 256 + tid;
    const int row = cid >> 5;
    const int c8  = (cid & 31) * 8;         // column base within this ng's 256
    const half8 v = *(const half8*)&s_out[row * 264 + c8];
    const int phi = (c8 >> 6) * 256 + ng * 64 + (c8 & 63); // block-major permute
    *(half8*)(g_gx + (size_t)(mb * 64 + row) * GATES + phi) = v;
  }
}

// ---- recurrent kernel: 63 clusters x 4 blocks, W_hh slice in VGPRs --------
__global__ __launch_bounds__(256, 1) void rec_kernel(
    const float* __restrict__ W_out, const float* __restrict__ b_out,
    float* __restrict__ y) {
  __shared__ _Float16 s_h[16 * 264];   // gathered full h (A-frag friendly)
  __shared__ float    s_g[16 * 260];   // recurrent gate pre-acts (stride 260: 2-way free)
  __shared__ _Float16 s_gx[16 * 264];  // gx slice for this step
  __shared__ _Float16 s_hl[16 * 64];   // this block's new h slice

  const int tid  = threadIdx.x;
  const int lane = tid & 63;
  const int w    = tid >> 6;
  const int c    = blockIdx.x >> 2;    // cluster
  const int b    = blockIdx.x & 3;     // dim-slice owner

  // ---- one-time: load this block's 128KB W_hh slice into VGPR B-fragments
  // local gate l = q*64 + dd ; tile j = q*4 + sub (dd = sub*16 + n16)
  // global gate tile nt = q*16 + b*4 + sub ; wave w owns tiles j = 4w..4w+3
  half8 wf[4][8];
  #pragma unroll
  for (int jj = 0; jj < 4; ++jj) {
    const int j = w * 4 + jj;
    const int nt = (j >> 2) * 16 + b * 4 + (j & 3);
    #pragma unroll
    for (int ks = 0; ks < 8; ++ks)
      wf[jj][ks] = *(const half8*)(g_whf + ((size_t)(nt * 8 + ks) * 64 + lane) * 8);
  }

  // cell-update ownership: pt = tid>>4, dims dd = (tid&15) + 16v (v=0..3)
  const int pt = tid >> 4;
  const int ds = tid & 15;
  float cst[4];
  float wo[4];
  #pragma unroll
  for (int v = 0; v < 4; ++v) {
    cst[v] = 0.f;
    wo[v] = W_out[b * 64 + ds + 16 * v];
  }
  const float bo = (b == 0) ? b_out[0] : 0.f;
  const int n_pt = c * CPTS + pt;                 // grid point (may be >=NGRID)
  const int row_clamp_base = (n_pt < NGRID) ? n_pt : (NGRID - 1);

  // zero s_h (h_0 = 0)
  for (int i = tid; i < 16 * 264 / 2; i += 256) ((unsigned int*)s_h)[i] = 0u;
  __syncthreads();

  const int a_off = (lane & 15) * 264 + (lane >> 4) * 8;

  for (int t = 0; t < NT; ++t) {
    // 1) issue gx prefetch for this step (independent of h; hides HBM latency)
    half8 gxr[2];
    int gx_pt[2], gx_off[2];
    #pragma unroll
    for (int k = 0; k < 2; ++k) {
      const int chunk = tid * 2 + k;              // 0..511
      gx_pt[k]  = chunk >> 5;
      gx_off[k] = (chunk & 31) * 8;
      const int np = c * CPTS + gx_pt[k];
      const int rn = (np < NGRID) ? np : (NGRID - 1);
      gxr[k] = *(const half8*)(g_gx + ((size_t)t * NGRID + rn) * GATES + b * 256 + gx_off[k]);
    }

    // 2) wait for all 4 blocks to have published h_t, then gather it
    if (t > 0) {
      if (tid == 0) {
        const unsigned int target = 4u * (unsigned int)t;
        int tries = 0;
        while (__hip_atomic_load(&g_cnt[c], __ATOMIC_ACQUIRE,
                                 __HIP_MEMORY_SCOPE_AGENT) < target &&
               ++tries < 2000000) {
          __builtin_amdgcn_s_sleep(1);
        }
      }
      __syncthreads();
      const u64* src = &g_hx[t & 1][c][0];
      #pragma unroll
      for (int k = 0; k < 4; ++k) {
        const int f = tid + 256 * k;              // 0..1023 u64 chunks
        const u64 v = __hip_atomic_load(&src[f], __ATOMIC_RELAXED,
                                        __HIP_MEMORY_SCOPE_AGENT);
        *(u64*)&s_h[(f >> 6) * 264 + (f & 63) * 4] = v;
      }
    }
    __syncthreads(); // s_h(t) ready

    // 3) GEMM: gates_rec = h_t @ W_hh_slice.T  (weights in registers)
    half8 af[8];
    #pragma unroll
    for (int ks = 0; ks < 8; ++ks)
      af[ks] = *(const half8*)&s_h[a_off + ks * 32];

    #pragma unroll
    for (int jj = 0; jj < 4; ++jj) {
      floatx4 c0 = (floatx4){0.f, 0.f, 0.f, 0.f};
      floatx4 c1 = (floatx4){0.f, 0.f, 0.f, 0.f};
      #pragma unroll
      for (int ks = 0; ks < 4; ++ks)
        c0 = __builtin_amdgcn_mfma_f32_16x16x32_f16(af[ks], wf[jj][ks], c0, 0, 0, 0);
      #pragma unroll
      for (int ks = 4; ks < 8; ++ks)
        c1 = __builtin_amdgcn_mfma_f32_16x16x32_f16(af[ks], wf[jj][ks], c1, 0, 0, 0);
      const floatx4 acc = c0 + c1;
      const int l0 = (w * 4 + jj) * 16 + (lane & 15);
      #pragma unroll
      for (int r = 0; r < 4; ++r)
        s_g[((lane >> 4) * 4 + r) * 260 + l0] = acc[r];
    }

    // stash gx into LDS (registers arrived by now)
    #pragma unroll
    for (int k = 0; k < 2; ++k)
      *(half8*)&s_gx[gx_pt[k] * 264 + gx_off[k]] = gxr[k];
    __syncthreads(); // s_g, s_gx ready

    // 4) cell update for our 64 dims x our pt
    {
      const float* gp = &s_g[pt * 260];
      const _Float16* xp = &s_gx[pt * 264];
      float yp = 0.f;
      #pragma unroll
      for (int v = 0; v < 4; ++v) {
        const int dd = ds + 16 * v;
        const float gi = gp[dd]       + (float)xp[dd];
        const float gf = gp[64 + dd]  + (float)xp[64 + dd];
        const float gg = gp[128 + dd] + (float)xp[128 + dd];
        const float go = gp[192 + dd] + (float)xp[192 + dd];
        const float i_ = fsig(gi);
        const float f_ = fsig(gf);
        const float g_ = ftanh(gg);
        const float o_ = fsig(go);
        cst[v] = f_ * cst[v] + i_ * g_;
        const float h = o_ * ftanh(cst[v]);
        s_hl[pt * 64 + dd] = (_Float16)h;
        yp += wo[v] * h;
      }
      // reduce y partial across the 16 lanes sharing pt, then atomicAdd
      yp += __shfl_xor(yp, 1);
      yp += __shfl_xor(yp, 2);
      yp += __shfl_xor(yp, 4);
      yp += __shfl_xor(yp, 8);
      if (ds == 0 && n_pt < NGRID)
        atomicAdd(&y[t * NGRID + n_pt], yp + bo);
    }
    __syncthreads(); // s_hl ready

    // 5) publish our h_{t+1} slice (LLC-direct) + release counter
    if (t < NT - 1) {
      const u64 hv = *(const u64*)&s_hl[tid * 4];
      const int idx = (tid >> 4) * 64 + b * 16 + (tid & 15);
      __hip_atomic_store(&g_hx[(t + 1) & 1][c][idx], hv, __ATOMIC_RELAXED,
                         __HIP_MEMORY_SCOPE_AGENT);
      __syncthreads(); // drains vmcnt: all lanes' stores complete before release
      if (tid == 0)
        __hip_atomic_fetch_add(&g_cnt[c], 1u, __ATOMIC_RELEASE,
                               __HIP_MEMORY_SCOPE_AGENT);
    }
    (void)row_clamp_base;
  }
}

extern "C" void kernel_launch(void* const* d_in, const int* in_sizes, int n_in,
                              void* d_out, int out_size, void* d_ws, size_t ws_size,
                              hipStream_t stream) {
  (void)in_sizes; (void)n_in; (void)out_size; (void)d_ws; (void)ws_size;
  const float* x     = (const float*)d_in[0];
  // d_in[1] = wt_ih (zeros in eval mode, unused)
  const float* W_in  = (const float*)d_in[2];
  const float* b_in  = (const float*)d_in[3];
  const float* W_ih  = (const float*)d_in[4];
  const float* W_hh  = (const float*)d_in[5];
  const float* b_ih  = (const float*)d_in[6];
  const float* b_hh  = (const float*)d_in[7];
  const float* W_out = (const float*)d_in[8];
  const float* b_out = (const float*)d_in[9];
  float* y           = (float*)d_out;

  hipLaunchKernelGGL(init_kernel, dim3((MROWS + 255) / 256), dim3(256), 0, stream, y);
  hipLaunchKernelGGL(pack_wf_kernel, dim3(256), dim3(256), 0, stream, W_ih, W_hh);
  hipLaunchKernelGGL(x0f_kernel, dim3(MBLK), dim3(256), 0, stream, x, W_in, b_in);
  hipLaunchKernelGGL(gx_kernel, dim3(MBLK * 4), dim3(256), 0, stream, b_ih, b_hh);
  hipLaunchKernelGGL(rec_kernel, dim3(NCL * 4), dim3(256), 0, stream, W_out, b_out, y);
}

// Round 6
// 1923.607 us; speedup vs baseline: 3.8770x; 3.2415x over previous
//
#include <hip/hip_runtime.h>
#include <hip/hip_fp16.h>

#define NT    365
#define NGRID 1000
#define NXI   20
#define HID   256
#define GATES 1024
#define MROWS 365000          // NT*NGRID
#define MBLK  5704            // ceil(MROWS/64)
#define MPAD  (MBLK * 64)
#define NCL   63              // clusters (16 pts each, last one ragged)
#define CPTS  16              // grid points per cluster
#define HXN   (2 * NCL * 4 * 1024)  // u64 slots in g_hx2 = 516096

typedef _Float16 half8 __attribute__((ext_vector_type(8)));
typedef _Float16 half4 __attribute__((ext_vector_type(4)));
typedef float floatx4 __attribute__((ext_vector_type(4)));
typedef unsigned long long u64;

#define SENT 0xFFFFFFFFFFFFFFFFull   // 4x fp16 NaN — unreachable by valid math

// Module-scope globals (d_ws is too small). Fully rewritten / reset each launch.
__device__ _Float16 g_x0f[(size_t)MPAD * HID];    // x0 in A-fragment layout
__device__ _Float16 g_gx[(size_t)MPAD * GATES];   // gx, block-permuted columns
__device__ _Float16 g_wif[64 * 8 * 512];          // W_ih B-fragments
__device__ _Float16 g_whf[64 * 8 * 512];          // W_hh B-fragments
// h exchange: [parity][cluster][consumer-block copy][1024 chunks of u64].
// Sentinel protocol: chunk==SENT means "not yet published for this round".
// The data is its own ready-flag — no cross-address ordering assumptions
// (that was round 5's race: counter visible before data at the LLC).
__device__ u64 g_hx2[2][NCL][4][1024];

__device__ __forceinline__ float fsig(float x) {
  return __fdividef(1.f, 1.f + __expf(-x));
}
__device__ __forceinline__ float ftanh(float x) {
  return 1.f - __fdividef(2.f, __expf(2.f * x) + 1.f);
}

// ---- init: zero y (atomicAdd target), sentinel-fill the h exchange --------
__global__ __launch_bounds__(256) void init_kernel(float* __restrict__ y) {
  const int i = blockIdx.x * 256 + threadIdx.x;   // grid covers 516096
  if (i < MROWS) y[i] = 0.f;
  if (i < HXN) (&g_hx2[0][0][0][0])[i] = SENT;
}

// ---- pack W_ih / W_hh into MFMA B-fragment layout -------------------------
__global__ __launch_bounds__(256) void pack_wf_kernel(
    const float* __restrict__ W_ih, const float* __restrict__ W_hh) {
  const int gid  = blockIdx.x * 256 + threadIdx.x;  // 0..65535
  const int mat  = gid >> 15;
  const int rem  = gid & 32767;
  const int tile = rem >> 9;
  const int ks   = (rem >> 6) & 7;
  const int lane = rem & 63;
  const int n    = tile * 16 + (lane & 15);
  const int k0   = ks * 32 + (lane >> 4) * 8;
  const float* src = (mat ? W_hh : W_ih) + n * HID + k0;
  _Float16* dst = (mat ? g_whf : g_wif) + ((tile * 8 + ks) * 64 + lane) * 8;
  const float4 a = *(const float4*)(src);
  const float4 b = *(const float4*)(src + 4);
  half8 h;
  h[0] = (_Float16)a.x; h[1] = (_Float16)a.y; h[2] = (_Float16)a.z; h[3] = (_Float16)a.w;
  h[4] = (_Float16)b.x; h[5] = (_Float16)b.y; h[6] = (_Float16)b.z; h[7] = (_Float16)b.w;
  *(half8*)dst = h;
}

// ---- x0 = relu(x @ W_in.T + b_in) in A-fragment layout --------------------
__global__ __launch_bounds__(256) void x0f_kernel(
    const float* __restrict__ x, const float* __restrict__ W_in,
    const float* __restrict__ b_in) {
  __shared__ float s_x[64 * NXI];
  __shared__ _Float16 s_x0[64 * 264];

  const int tid = threadIdx.x;
  const int m0  = blockIdx.x * 64;

  #pragma unroll
  for (int i = 0; i < 5; ++i) {
    const int idx = i * 256 + tid;
    size_t g = (size_t)m0 * NXI + idx;
    const size_t gmax = (size_t)MROWS * NXI - 1;
    if (g > gmax) g = gmax;
    s_x[idx] = x[g];
  }
  float wv[NXI];
  #pragma unroll
  for (int k = 0; k < NXI; ++k) wv[k] = W_in[tid * NXI + k];
  const float bv = b_in[tid];
  __syncthreads();

  for (int r = 0; r < 64; ++r) {
    float acc = bv;
    #pragma unroll
    for (int q = 0; q < 5; ++q) {
      const float4 xa = *(const float4*)&s_x[r * NXI + q * 4];
      acc += xa.x * wv[q * 4 + 0] + xa.y * wv[q * 4 + 1] +
             xa.z * wv[q * 4 + 2] + xa.w * wv[q * 4 + 3];
    }
    s_x0[r * 264 + tid] = (_Float16)fmaxf(acc, 0.f);
  }
  __syncthreads();

  #pragma unroll
  for (int it = 0; it < 8; ++it) {
    const int work = it * 256 + tid;
    const int f    = work >> 6;
    const int l    = work & 63;
    const int mtl  = f >> 3;
    const int kt   = f & 7;
    const int r    = mtl * 16 + (l & 15);
    const int c    = kt * 32 + (l >> 4) * 8;
    const half8 v  = *(const half8*)&s_x0[r * 264 + c];
    const int mt   = (m0 >> 4) + mtl;
    *(half8*)(g_x0f + ((size_t)(mt * 8 + kt) * 64 + l) * 8) = v;
  }
}

// ---- gx = x0 @ W_ih.T + (b_ih + b_hh), columns permuted to block-major ----
// column g stored at phi(g) = ((g>>6)&3)*256 + (g>>8)*64 + (g&63)
__global__ __launch_bounds__(256) void gx_kernel(
    const float* __restrict__ b_ih, const float* __restrict__ b_hh) {
  __shared__ _Float16 s_out[64 * 264];

  const int tid  = threadIdx.x;
  const int lane = tid & 63;
  const int w    = tid >> 6;
  const int mb   = blockIdx.x >> 2;
  const int ng   = blockIdx.x & 3;

  floatx4 acc[4][4];
  #pragma unroll
  for (int mi = 0; mi < 4; ++mi)
    #pragma unroll
    for (int ni = 0; ni < 4; ++ni) acc[mi][ni] = (floatx4){0.f, 0.f, 0.f, 0.f};

  #pragma unroll
  for (int ks = 0; ks < 8; ++ks) {
    half8 a[4], b[4];
    #pragma unroll
    for (int mi = 0; mi < 4; ++mi) {
      const int mt = mb * 4 + mi;
      a[mi] = *(const half8*)(g_x0f + ((size_t)(mt * 8 + ks) * 64 + lane) * 8);
    }
    #pragma unroll
    for (int ni = 0; ni < 4; ++ni) {
      const int nt = ng * 16 + w * 4 + ni;
      b[ni] = *(const half8*)(g_wif + ((size_t)(nt * 8 + ks) * 64 + lane) * 8);
    }
    #pragma unroll
    for (int mi = 0; mi < 4; ++mi)
      #pragma unroll
      for (int ni = 0; ni < 4; ++ni)
        acc[mi][ni] = __builtin_amdgcn_mfma_f32_16x16x32_f16(a[mi], b[ni], acc[mi][ni], 0, 0, 0);
  }

  #pragma unroll
  for (int ni = 0; ni < 4; ++ni) {
    const int g = ng * 256 + (w * 4 + ni) * 16 + (lane & 15);
    const float bias = b_ih[g] + b_hh[g];
    const int colw = (w * 4 + ni) * 16 + (lane & 15);
    #pragma unroll
    for (int mi = 0; mi < 4; ++mi) {
      #pragma unroll
      for (int r = 0; r < 4; ++r) {
        const int row = mi * 16 + (lane >> 4) * 4 + r;
        s_out[row * 264 + colw] = (_Float16)(acc[mi][ni][r] + bias);
      }
    }
  }
  __syncthreads();

  #pragma unroll
  for (int i = 0; i < 8; ++i) {
    const int cid = i * 256 + tid;
    const int row = cid >> 5;
    const int c8  = (cid & 31) * 8;         // column base within this ng's 256
    const half8 v = *(const half8*)&s_out[row * 264 + c8];
    const int phi = (c8 >> 6) * 256 + ng * 64 + (c8 & 63); // block-major permute
    *(half8*)(g_gx + (size_t)(mb * 64 + row) * GATES + phi) = v;
  }
}

// ---- recurrent kernel: 63 clusters x 4 blocks, W_hh slice in VGPRs --------
// Sentinel h-exchange (see g_hx2 comment). All traffic relaxed agent-scope
// (sc1 -> coherent LLC, no L1/L2 cache maintenance). Per-thread poll; a
// spin-cap miss injects NaN -> loud failure, never silent staleness.
__global__ __launch_bounds__(256, 1) void rec_kernel(
    const float* __restrict__ W_out, const float* __restrict__ b_out,
    float* __restrict__ y) {
  __shared__ _Float16 s_h[16 * 264];   // gathered full h (A-frag friendly)
  __shared__ float    s_g[16 * 260];   // recurrent gate pre-acts
  __shared__ _Float16 s_gx[16 * 264];  // gx slice for this step

  const int tid  = threadIdx.x;
  const int lane = tid & 63;
  const int w    = tid >> 6;
  const int c    = blockIdx.x >> 2;    // cluster
  const int b    = blockIdx.x & 3;     // dim-slice owner

  // ---- one-time: load this block's 128KB W_hh slice into register B-frags
  half8 wf[4][8];
  #pragma unroll
  for (int jj = 0; jj < 4; ++jj) {
    const int j = w * 4 + jj;
    const int nt = (j >> 2) * 16 + b * 4 + (j & 3);
    #pragma unroll
    for (int ks = 0; ks < 8; ++ks)
      wf[jj][ks] = *(const half8*)(g_whf + ((size_t)(nt * 8 + ks) * 64 + lane) * 8);
  }

  // cell-update ownership: pt = tid>>4, contiguous local dims 4q..4q+3
  const int pt = tid >> 4;
  const int q  = tid & 15;
  floatx4 cst = (floatx4){0.f, 0.f, 0.f, 0.f};
  const floatx4 wo = *(const floatx4*)(W_out + b * 64 + q * 4);
  const float bo = (b == 0) ? b_out[0] : 0.f;
  const int n_pt = c * CPTS + pt;                 // grid point (may be >=NGRID)

  // zero s_h (h_0 = 0)
  for (int i = tid; i < 16 * 264 / 2; i += 256) ((unsigned int*)s_h)[i] = 0u;
  __syncthreads();

  const int a_off = (lane & 15) * 264 + (lane >> 4) * 8;
  const int hx_idx = pt * 64 + b * 16 + q;        // this thread's publish chunk

  for (int t = 0; t < NT; ++t) {
    // 1) issue gx prefetch for this step (independent of h; hides HBM latency)
    half8 gxr[2];
    int gx_pt[2], gx_off[2];
    #pragma unroll
    for (int k = 0; k < 2; ++k) {
      const int chunk = tid * 2 + k;              // 0..511
      gx_pt[k]  = chunk >> 5;
      gx_off[k] = (chunk & 31) * 8;
      const int np = c * CPTS + gx_pt[k];
      const int rn = (np < NGRID) ? np : (NGRID - 1);
      gxr[k] = *(const half8*)(g_gx + ((size_t)t * NGRID + rn) * GATES + b * 256 + gx_off[k]);
    }

    // 2) gather h_t from our copy region: poll each chunk until published
    if (t > 0) {
      u64* src = &g_hx2[t & 1][c][b][0];
      u64 v[4];
      #pragma unroll
      for (int k = 0; k < 4; ++k)
        v[k] = __hip_atomic_load(&src[tid + 256 * k], __ATOMIC_RELAXED,
                                 __HIP_MEMORY_SCOPE_AGENT);
      #pragma unroll
      for (int k = 0; k < 4; ++k) {
        const int f = tid + 256 * k;
        int tries = 0;
        while (v[k] == SENT && ++tries < 1000000)
          v[k] = __hip_atomic_load(&src[f], __ATOMIC_RELAXED,
                                   __HIP_MEMORY_SCOPE_AGENT);
        *(u64*)&s_h[(f >> 6) * 264 + (f & 63) * 4] = v[k];
      }
      #pragma unroll
      for (int k = 0; k < 4; ++k)       // re-arm for reuse at t+2
        __hip_atomic_store(&src[tid + 256 * k], SENT, __ATOMIC_RELAXED,
                           __HIP_MEMORY_SCOPE_AGENT);
    }
    __syncthreads(); // s_h(t) ready; also drains the re-arm stores (vmcnt)

    // 3) GEMM: gates_rec = h_t @ W_hh_slice.T  (weights in registers)
    half8 af[8];
    #pragma unroll
    for (int ks = 0; ks < 8; ++ks)
      af[ks] = *(const half8*)&s_h[a_off + ks * 32];

    #pragma unroll
    for (int jj = 0; jj < 4; ++jj) {
      floatx4 c0 = (floatx4){0.f, 0.f, 0.f, 0.f};
      floatx4 c1 = (floatx4){0.f, 0.f, 0.f, 0.f};
      #pragma unroll
      for (int ks = 0; ks < 4; ++ks)
        c0 = __builtin_amdgcn_mfma_f32_16x16x32_f16(af[ks], wf[jj][ks], c0, 0, 0, 0);
      #pragma unroll
      for (int ks = 4; ks < 8; ++ks)
        c1 = __builtin_amdgcn_mfma_f32_16x16x32_f16(af[ks], wf[jj][ks], c1, 0, 0, 0);
      const floatx4 acc = c0 + c1;
      const int l0 = (w * 4 + jj) * 16 + (lane & 15);
      #pragma unroll
      for (int r = 0; r < 4; ++r)
        s_g[((lane >> 4) * 4 + r) * 260 + l0] = acc[r];
    }

    // stash gx into LDS (registers arrived by now)
    #pragma unroll
    for (int k = 0; k < 2; ++k)
      *(half8*)&s_gx[gx_pt[k] * 264 + gx_off[k]] = gxr[k];
    __syncthreads(); // s_g, s_gx ready

    // 4) cell update: thread (pt, q) owns contiguous dims 4q..4q+3
    {
      const float*    gp = &s_g[pt * 260];
      const _Float16* xp = &s_gx[pt * 264];
      const floatx4 gi4 = *(const floatx4*)&gp[q * 4];
      const floatx4 gf4 = *(const floatx4*)&gp[64 + q * 4];
      const floatx4 gg4 = *(const floatx4*)&gp[128 + q * 4];
      const floatx4 go4 = *(const floatx4*)&gp[192 + q * 4];
      const half4 xi4 = *(const half4*)&xp[q * 4];
      const half4 xf4 = *(const half4*)&xp[64 + q * 4];
      const half4 xg4 = *(const half4*)&xp[128 + q * 4];
      const half4 xo4 = *(const half4*)&xp[192 + q * 4];
      float yp = 0.f;
      union { u64 u; _Float16 h[4]; } hv;
      #pragma unroll
      for (int j = 0; j < 4; ++j) {
        const float gi = gi4[j] + (float)xi4[j];
        const float gf = gf4[j] + (float)xf4[j];
        const float gg = gg4[j] + (float)xg4[j];
        const float go = go4[j] + (float)xo4[j];
        const float i_ = fsig(gi);
        const float f_ = fsig(gf);
        const float g_ = ftanh(gg);
        const float o_ = fsig(go);
        cst[j] = f_ * cst[j] + i_ * g_;
        const float h = o_ * ftanh(cst[j]);
        hv.h[j] = (_Float16)h;
        yp += wo[j] * h;
      }
      // reduce y partial across the 16 lanes sharing pt, then atomicAdd
      yp += __shfl_xor(yp, 1);
      yp += __shfl_xor(yp, 2);
      yp += __shfl_xor(yp, 4);
      yp += __shfl_xor(yp, 8);
      if (q == 0 && n_pt < NGRID)
        atomicAdd(&y[t * NGRID + n_pt], yp + bo);

      // 5) publish h_{t+1} chunk straight from registers into all 4 copies
      if (t < NT - 1) {
        u64* dst = &g_hx2[(t + 1) & 1][c][0][0];
        #pragma unroll
        for (int b2 = 0; b2 < 4; ++b2)
          __hip_atomic_store(dst + b2 * 1024 + hx_idx, hv.u, __ATOMIC_RELAXED,
                             __HIP_MEMORY_SCOPE_AGENT);
      }
    }
    // no end-of-step barrier: next iteration's s_h-ready barrier suffices
  }
}

extern "C" void kernel_launch(void* const* d_in, const int* in_sizes, int n_in,
                              void* d_out, int out_size, void* d_ws, size_t ws_size,
                              hipStream_t stream) {
  (void)in_sizes; (void)n_in; (void)out_size; (void)d_ws; (void)ws_size;
  const float* x     = (const float*)d_in[0];
  // d_in[1] = wt_ih (zeros in eval mode, unused)
  const float* W_in  = (const float*)d_in[2];
  const float* b_in  = (const float*)d_in[3];
  const float* W_ih  = (const float*)d_in[4];
  const float* W_hh  = (const float*)d_in[5];
  const float* b_ih  = (const float*)d_in[6];
  const float* b_hh  = (const float*)d_in[7];
  const float* W_out = (const float*)d_in[8];
  const float* b_out = (const float*)d_in[9];
  float* y           = (float*)d_out;

  hipLaunchKernelGGL(init_kernel, dim3(HXN / 256), dim3(256), 0, stream, y);
  hipLaunchKernelGGL(pack_wf_kernel, dim3(256), dim3(256), 0, stream, W_ih, W_hh);
  hipLaunchKernelGGL(x0f_kernel, dim3(MBLK), dim3(256), 0, stream, x, W_in, b_in);
  hipLaunchKernelGGL(gx_kernel, dim3(MBLK * 4), dim3(256), 0, stream, b_ih, b_hh);
  hipLaunchKernelGGL(rec_kernel, dim3(NCL * 4), dim3(256), 0, stream, W_out, b_out, y);
}